// Round 1
// baseline (28213.699 us; speedup 1.0000x reference)
//
#include <hip/hip_runtime.h>
#include <math.h>

// EKF over T steps: strictly sequential nonlinear recurrence.
// Strategy: parallel "pack" kernel precomputes all state-independent per-step
// quantities into one float4/step; a single-lane sequential kernel runs the
// recurrence with symmetric-P (6 element) algebra and prefetch distance 4.

__device__ __forceinline__ float softplus_f(float x) {
    // jax.nn.softplus = logaddexp(x, 0) = max(x,0) + log1p(exp(-|x|))
    return fmaxf(x, 0.0f) + log1pf(__expf(-fabsf(x)));
}

struct EKFConsts {
    float kap, xi2, d2, f1, f2, xi2DT, crossDT, cw;
};
struct EKFState {
    float w0, w1, w2, p00, p01, p02, p11, p12, p22;
};

__device__ __forceinline__ float4 ekf_step(EKFState& s, const EKFConsts& c,
                                           float obs, float kterm, float c0dt, float c1dt)
{
    const float DTv  = 1.0f / 262.0f;
    const float ETA  = 1e-6f;
    const float ETA2 = 2e-6f;

    // term = kap * softplus(theta+g) * clip(exp(-w0),0,1); kterm precomputed
    float e = __expf(-s.w0);
    e = fminf(e, 1.0f);                    // exp >= 0, only upper clip matters
    float term = kterm * e;
    term = (term != term) ? 0.0f : term;   // isnan guard (matches reference)
    float d0 = 1.0f - term;                // Psi[0,0]

    float sigma  = __expf(0.5f * s.w0);
    float sigma2 = sigma * sigma;

    // w_pred
    float w0p = fmaf(term + c.cw, DTv, s.w0);        // cw = xi2/2 - kap
    float w1p = s.w1 + fmaf(s.w2, DTv, c0dt);        // w1 + (w2 + c0)*DT
    float w2p = fmaf(c.d2, s.w2, c1dt);              // w2 + (-a1*w2 + c1)*DT

    // P_pred = Psi P Psi^T + R, symmetric (6 elements); diag gets 2*ETA total
    float pp00 = fmaf(d0 * d0, s.p00, c.xi2DT) + ETA2;
    float pp01 = d0 * fmaf(DTv, s.p02, s.p01);
    float pp02 = fmaf(d0 * c.d2, s.p02, sigma * c.crossDT);
    float pp11 = s.p11 + 2.0f * DTv * s.p12 + (DTv * DTv) * s.p22 + ETA2;
    float pp12 = c.d2 * fmaf(DTv, s.p22, s.p12);
    float pp22 = fmaf(c.d2 * c.d2, s.p22, sigma2 * DTv) + ETA2;

    // observation update; phi_row = [0, f1, f2]
    float xp    = c.f1 * w1p + c.f2 * w2p;           // x_pred
    float sig2p = __expf(w0p);
    float u0 = c.f1 * pp01 + c.f2 * pp02;            // u = P_pred @ phi_row
    float u1 = c.f1 * pp11 + c.f2 * pp12;
    float u2 = c.f1 * pp12 + c.f2 * pp22;
    float Q  = c.f1 * u1 + c.f2 * u2 + fmaf(sig2p, DTv, ETA2);
    float rQ = __builtin_amdgcn_rcpf(Q);             // ~1 ulp; EKF is contractive
    float K0 = u0 * rQ, K1 = u1 * rQ, K2 = u2 * rQ;
    float innov = obs - xp;

    s.w0 = fmaf(K0, innov, w0p);
    s.w1 = fmaf(K1, innov, w1p);
    s.w2 = fmaf(K2, innov, w2p);
    // P_post = P_pred - K u^T (symmetric), + I*ETA
    const float ETAd = 1e-6f;
    s.p00 = pp00 - K0 * u0 + ETAd;
    s.p01 = pp01 - K0 * u1;
    s.p02 = pp02 - K0 * u2;
    s.p11 = pp11 - K1 * u1 + ETAd;
    s.p12 = pp12 - K1 * u2;
    s.p22 = pp22 - K2 * u2 + ETAd;

    return make_float4(xp, s.w0, s.w1, s.w2);
}

// Parallel pre-pass: pack (obs, kap*softplus(theta+g), c0*DT, c1*DT) per step.
__global__ void ekf_pack(const float* __restrict__ obs, const float* __restrict__ g,
                         const float2* __restrict__ carma,
                         const float* __restrict__ ptheta, const float* __restrict__ pkappa,
                         float4* __restrict__ ws, int n)
{
    int i = blockIdx.x * blockDim.x + threadIdx.x;
    if (i >= n) return;
    const float DTv = 1.0f / 262.0f;
    float kap = softplus_f(pkappa[0]);
    float kt  = kap * softplus_f(ptheta[0] + g[i]);
    float2 cv = carma[i];
    ws[i] = make_float4(obs[i], kt, cv.x * DTv, cv.y * DTv);
}

__device__ __forceinline__ void load_consts_state(
    EKFConsts& c, EKFState& s,
    const float* w0in, const float* P0,
    const float* pb0, const float* pb1, const float* pa1,
    const float* pkappa, const float* pxi, const float* prho)
{
    const float DTv = 1.0f / 262.0f;
    float b0 = pb0[0], b1 = pb1[0], a1 = pa1[0];
    c.kap  = softplus_f(pkappa[0]);
    float xi_  = softplus_f(pxi[0]);
    float rho_ = tanhf(prho[0]);
    c.xi2     = xi_ * xi_;
    c.d2      = 1.0f - a1 * DTv;
    c.f1      = b0 * DTv;
    c.f2      = b1 * DTv;
    c.xi2DT   = c.xi2 * DTv;
    c.crossDT = xi_ * rho_ * DTv;
    c.cw      = 0.5f * c.xi2 - c.kap;
    s.w0 = w0in[0]; s.w1 = w0in[1]; s.w2 = w0in[2];
    s.p00 = P0[0]; s.p01 = P0[1]; s.p02 = P0[2];
    s.p11 = P0[4]; s.p12 = P0[5]; s.p22 = P0[8];
}

// Sequential recurrence, one lane, prefetch distance 4.
__global__ void __launch_bounds__(64, 1) ekf_seq(
    const float4* __restrict__ ws, float4* __restrict__ out, int n,
    const float* __restrict__ w0in, const float* __restrict__ P0,
    const float* __restrict__ pb0, const float* __restrict__ pb1,
    const float* __restrict__ pa1, const float* __restrict__ pkappa,
    const float* __restrict__ pxi, const float* __restrict__ prho)
{
    if (threadIdx.x != 0) return;
    EKFConsts c; EKFState s;
    load_consts_state(c, s, w0in, P0, pb0, pb1, pa1, pkappa, pxi, prho);

    constexpr int U = 4;
    float4 buf[U];
    int t = 0;
    if (n >= U) {
        #pragma unroll
        for (int j = 0; j < U; ++j) buf[j] = ws[j];
        for (t = 0; t + U <= n; t += U) {
            float4 nbuf[U];
            int base = (t + 2 * U <= n) ? (t + U) : t;  // last block: harmless reload
            #pragma unroll
            for (int j = 0; j < U; ++j) nbuf[j] = ws[base + j];
            #pragma unroll
            for (int j = 0; j < U; ++j) {
                float4 x = buf[j];
                out[t + j] = ekf_step(s, c, x.x, x.y, x.z, x.w);
            }
            #pragma unroll
            for (int j = 0; j < U; ++j) buf[j] = nbuf[j];
        }
    }
    for (; t < n; ++t) {  // tail (n % U != 0)
        float4 x = ws[t];
        out[t] = ekf_step(s, c, x.x, x.y, x.z, x.w);
    }
}

// Fallback if workspace is too small: load raw inputs, softplus inline.
__global__ void __launch_bounds__(64, 1) ekf_seq_raw(
    const float* __restrict__ obs, const float* __restrict__ g,
    const float2* __restrict__ carma, float4* __restrict__ out, int n,
    const float* __restrict__ w0in, const float* __restrict__ P0,
    const float* __restrict__ pb0, const float* __restrict__ pb1,
    const float* __restrict__ pa1, const float* __restrict__ pkappa,
    const float* __restrict__ ptheta, const float* __restrict__ pxi,
    const float* __restrict__ prho)
{
    if (threadIdx.x != 0) return;
    EKFConsts c; EKFState s;
    load_consts_state(c, s, w0in, P0, pb0, pb1, pa1, pkappa, pxi, prho);
    const float DTv = 1.0f / 262.0f;
    float theta = ptheta[0];
    for (int t = 0; t < n; ++t) {
        float kt = c.kap * softplus_f(theta + g[t]);
        float2 cv = carma[t];
        out[t] = ekf_step(s, c, obs[t], kt, cv.x * DTv, cv.y * DTv);
    }
}

extern "C" void kernel_launch(void* const* d_in, const int* in_sizes, int n_in,
                              void* d_out, int out_size, void* d_ws, size_t ws_size,
                              hipStream_t stream)
{
    const float*  obs   = (const float*)d_in[0];
    const float*  g     = (const float*)d_in[1];
    const float2* carma = (const float2*)d_in[2];
    const float*  w0    = (const float*)d_in[3];
    const float*  P0    = (const float*)d_in[4];
    const float*  b0    = (const float*)d_in[5];
    const float*  b1    = (const float*)d_in[6];
    const float*  a1    = (const float*)d_in[7];
    const float*  kappa = (const float*)d_in[8];
    const float*  theta = (const float*)d_in[9];
    const float*  xi    = (const float*)d_in[10];
    const float*  rho   = (const float*)d_in[11];
    int n = in_sizes[0];
    float4* out = (float4*)d_out;

    if (ws_size >= (size_t)n * sizeof(float4)) {
        float4* ws = (float4*)d_ws;
        ekf_pack<<<(n + 255) / 256, 256, 0, stream>>>(obs, g, carma, theta, kappa, ws, n);
        ekf_seq<<<1, 64, 0, stream>>>(ws, out, n, w0, P0, b0, b1, a1, kappa, xi, rho);
    } else {
        ekf_seq_raw<<<1, 64, 0, stream>>>(obs, g, carma, out, n,
                                          w0, P0, b0, b1, a1, kappa, theta, xi, rho);
    }
}

// Round 2
// 2971.020 us; speedup vs baseline: 9.4963x; 9.4963x over previous
//
#include <hip/hip_runtime.h>
#include <math.h>

// EKF, T sequential steps. Round-2 strategy: parallel-in-time sweeps.
// The filter is contractive (slowest mode w1: tau ~1540 steps), so split T
// into C=32 chunks of 4096 and run K=4 Jacobi sweeps S_{i+1} = F_chunk(S_i):
// chunks 0..K-1 become exact, the rest carry err ~ err0 * (e^-2.7)^(K-1).
// Sequential depth: 131072 -> 16384. A parallel pack kernel precomputes all
// state-independent per-step data into one float4/step.

#define DTV (1.0f/262.0f)

__device__ __forceinline__ float softplus_f(float x) {
    // jax.nn.softplus = max(x,0) + log1p(exp(-|x|))
    return fmaxf(x, 0.0f) + log1pf(__expf(-fabsf(x)));
}

struct EKFConsts { float kap, d2, d2sq, f1, f2, xi2DT, crossDT, cw; };
struct EKFState  { float w0, w1, w2, p00, p01, p02, p11, p12, p22; };

__device__ __forceinline__ void load_consts(EKFConsts& c,
    const float* pb0, const float* pb1, const float* pa1,
    const float* pkappa, const float* pxi, const float* prho)
{
    float b0 = pb0[0], b1 = pb1[0], a1 = pa1[0];
    c.kap = softplus_f(pkappa[0]);
    float xi_  = softplus_f(pxi[0]);
    float rho_ = tanhf(prho[0]);
    float xi2  = xi_ * xi_;
    c.d2      = 1.0f - a1 * DTV;
    c.d2sq    = c.d2 * c.d2;
    c.f1      = b0 * DTV;
    c.f2      = b1 * DTV;
    c.xi2DT   = xi2 * DTV;
    c.crossDT = xi_ * rho_ * DTV;
    c.cw      = 0.5f * xi2 - c.kap;
}

__device__ __forceinline__ float4 ekf_step(EKFState& s, const EKFConsts& c,
                                           float obs, float kterm, float c0dt, float c1dt)
{
    const float ETA  = 1e-6f;
    const float ETA2 = 2e-6f;

    float e = __expf(-s.w0);
    e = fminf(e, 1.0f);
    float term = kterm * e;
    term = (term != term) ? 0.0f : term;   // isnan guard (matches reference)
    float d0 = 1.0f - term;

    float sigma  = __expf(0.5f * s.w0);
    float sigma2 = sigma * sigma;
    float s2DT   = sigma2 * DTV;
    float tc     = term + c.cw;            // cw = xi2/2 - kap

    float w0p = fmaf(tc, DTV, s.w0);
    float w1p = s.w1 + fmaf(s.w2, DTV, c0dt);
    float w2p = fmaf(c.d2, s.w2, c1dt);

    // P_pred (symmetric, 6 el); diag picks up 2*ETA (R's eta + explicit eta)
    float pp00 = fmaf(d0 * d0, s.p00, c.xi2DT) + ETA2;
    float pp01 = d0 * fmaf(DTV, s.p02, s.p01);
    float pp02 = fmaf(d0 * c.d2, s.p02, sigma * c.crossDT);
    float pp11 = s.p11 + 2.0f * DTV * s.p12 + (DTV * DTV) * s.p22 + ETA2;
    float pp12 = c.d2 * fmaf(DTV, s.p22, s.p12);
    float pp22 = fmaf(c.d2sq, s.p22, s2DT) + ETA2;

    float xp = fmaf(c.f1, w1p, c.f2 * w2p);
    // sig2p = exp(w0p) = sigma2*exp(tc*DT) ~= sigma2*(1+tc*DT); rel err <1e-8
    float sig2p = fmaf(s2DT, tc, sigma2);

    float u0 = fmaf(c.f1, pp01, c.f2 * pp02);
    float u1 = fmaf(c.f1, pp11, c.f2 * pp12);
    float u2 = fmaf(c.f1, pp12, c.f2 * pp22);
    float Q  = fmaf(c.f1, u1, fmaf(c.f2, u2, fmaf(sig2p, DTV, ETA2)));
    float rQ = __builtin_amdgcn_rcpf(Q);
    float innov = obs - xp;
    float K0 = u0 * rQ, K1 = u1 * rQ, K2 = u2 * rQ;

    s.w0 = fmaf(K0, innov, w0p);
    s.w1 = fmaf(K1, innov, w1p);
    s.w2 = fmaf(K2, innov, w2p);
    // P_post = P_pred - K u^T; symmetric exactly since K = u/Q
    s.p00 = pp00 - K0 * u0 + ETA;
    s.p01 = pp01 - K0 * u1;
    s.p02 = pp02 - K0 * u2;
    s.p11 = pp11 - K1 * u1 + ETA;
    s.p12 = pp12 - K1 * u2;
    s.p22 = pp22 - K2 * u2 + ETA;

    return make_float4(xp, s.w0, s.w1, s.w2);
}

// Parallel pre-pass: pack (obs, kap*softplus(theta+g), c0*DT, c1*DT) per step.
__global__ void ekf_pack(const float* __restrict__ obs, const float* __restrict__ g,
                         const float2* __restrict__ carma,
                         const float* __restrict__ ptheta, const float* __restrict__ pkappa,
                         float4* __restrict__ ws, int n)
{
    int i = blockIdx.x * blockDim.x + threadIdx.x;
    if (i >= n) return;
    float kap = softplus_f(pkappa[0]);
    float kt  = kap * softplus_f(ptheta[0] + g[i]);
    float2 cv = carma[i];
    ws[i] = make_float4(obs[i], kt, cv.x * DTV, cv.y * DTV);
}

// Initial boundary-state guesses: every chunk starts from (w0, P0).
__global__ void ekf_init_states(float* __restrict__ st, int C,
                                const float* __restrict__ w0in,
                                const float* __restrict__ P0)
{
    int i = blockIdx.x * blockDim.x + threadIdx.x;
    if (i >= C * 12) return;
    int k = i % 12;
    float v;
    if      (k < 3)  v = w0in[k];
    else if (k == 3) v = P0[0];
    else if (k == 4) v = P0[1];
    else if (k == 5) v = P0[2];
    else if (k == 6) v = P0[4];
    else if (k == 7) v = P0[5];
    else if (k == 8) v = P0[8];
    else             v = 0.0f;
    st[i] = v;
}

// One Jacobi sweep: block i runs chunk i from st_in[i], writes end state to
// st_out[i+1]. Chunk 0 always starts from the true initial condition.
template<bool WRITE>
__global__ void __launch_bounds__(64, 1) ekf_sweep(
    const float4* __restrict__ ws, float4* __restrict__ out, int n, int L,
    const float* __restrict__ st_in, float* __restrict__ st_out,
    const float* __restrict__ w0in, const float* __restrict__ P0,
    const float* __restrict__ pb0, const float* __restrict__ pb1,
    const float* __restrict__ pa1, const float* __restrict__ pkappa,
    const float* __restrict__ pxi, const float* __restrict__ prho)
{
    if (threadIdx.x != 0) return;
    EKFConsts c; load_consts(c, pb0, pb1, pa1, pkappa, pxi, prho);
    EKFState s;
    int chunk = blockIdx.x, C = gridDim.x;
    if (chunk == 0) {
        s.w0 = w0in[0]; s.w1 = w0in[1]; s.w2 = w0in[2];
        s.p00 = P0[0]; s.p01 = P0[1]; s.p02 = P0[2];
        s.p11 = P0[4]; s.p12 = P0[5]; s.p22 = P0[8];
    } else {
        const float* sp = st_in + chunk * 12;
        s.w0 = sp[0]; s.w1 = sp[1]; s.w2 = sp[2];
        s.p00 = sp[3]; s.p01 = sp[4]; s.p02 = sp[5];
        s.p11 = sp[6]; s.p12 = sp[7]; s.p22 = sp[8];
    }
    int t0 = chunk * L;
    int tend = min(t0 + L, n);

    constexpr int U = 8;   // prefetch distance: ~8*50 = 400 cy, covers IC latency
    float4 buf[U];
    int t = t0;
    if (tend - t0 >= U) {
        #pragma unroll
        for (int j = 0; j < U; ++j) buf[j] = ws[t0 + j];
        for (t = t0; t + U <= tend; t += U) {
            float4 nbuf[U];
            int base = (t + 2 * U <= tend) ? (t + U) : t;  // last block: harmless reload
            #pragma unroll
            for (int j = 0; j < U; ++j) nbuf[j] = ws[base + j];
            #pragma unroll
            for (int j = 0; j < U; ++j) {
                float4 x = buf[j];
                float4 r = ekf_step(s, c, x.x, x.y, x.z, x.w);
                if (WRITE) out[t + j] = r;
            }
            #pragma unroll
            for (int j = 0; j < U; ++j) buf[j] = nbuf[j];
        }
    }
    for (; t < tend; ++t) {
        float4 x = ws[t];
        float4 r = ekf_step(s, c, x.x, x.y, x.z, x.w);
        if (WRITE) out[t] = r;
    }

    if (chunk + 1 < C) {
        float* sp = st_out + (chunk + 1) * 12;
        sp[0] = s.w0; sp[1] = s.w1; sp[2] = s.w2;
        sp[3] = s.p00; sp[4] = s.p01; sp[5] = s.p02;
        sp[6] = s.p11; sp[7] = s.p12; sp[8] = s.p22;
    }
}

// Fallback: exact single-lane sequential pass over raw inputs.
__global__ void __launch_bounds__(64, 1) ekf_seq_raw(
    const float* __restrict__ obs, const float* __restrict__ g,
    const float2* __restrict__ carma, float4* __restrict__ out, int n,
    const float* __restrict__ w0in, const float* __restrict__ P0,
    const float* __restrict__ pb0, const float* __restrict__ pb1,
    const float* __restrict__ pa1, const float* __restrict__ pkappa,
    const float* __restrict__ ptheta, const float* __restrict__ pxi,
    const float* __restrict__ prho)
{
    if (threadIdx.x != 0) return;
    EKFConsts c; load_consts(c, pb0, pb1, pa1, pkappa, pxi, prho);
    EKFState s;
    s.w0 = w0in[0]; s.w1 = w0in[1]; s.w2 = w0in[2];
    s.p00 = P0[0]; s.p01 = P0[1]; s.p02 = P0[2];
    s.p11 = P0[4]; s.p12 = P0[5]; s.p22 = P0[8];
    float theta = ptheta[0];
    for (int t = 0; t < n; ++t) {
        float kt = c.kap * softplus_f(theta + g[t]);
        float2 cv = carma[t];
        out[t] = ekf_step(s, c, obs[t], kt, cv.x * DTV, cv.y * DTV);
    }
}

extern "C" void kernel_launch(void* const* d_in, const int* in_sizes, int n_in,
                              void* d_out, int out_size, void* d_ws, size_t ws_size,
                              hipStream_t stream)
{
    const float*  obs   = (const float*)d_in[0];
    const float*  g     = (const float*)d_in[1];
    const float2* carma = (const float2*)d_in[2];
    const float*  w0    = (const float*)d_in[3];
    const float*  P0    = (const float*)d_in[4];
    const float*  b0    = (const float*)d_in[5];
    const float*  b1    = (const float*)d_in[6];
    const float*  a1    = (const float*)d_in[7];
    const float*  kappa = (const float*)d_in[8];
    const float*  theta = (const float*)d_in[9];
    const float*  xi    = (const float*)d_in[10];
    const float*  rho   = (const float*)d_in[11];
    int n = in_sizes[0];
    float4* out = (float4*)d_out;

    const int C = 32;                 // chunks (one wave each)
    int L = (n + C - 1) / C;          // 4096 for T=131072
    size_t need = (size_t)n * sizeof(float4) + (size_t)2 * C * 12 * sizeof(float);

    if (ws_size >= need && n >= C) {
        float4* wsf = (float4*)d_ws;
        float* stA = (float*)(wsf + n);
        float* stB = stA + C * 12;
        ekf_pack<<<(n + 255) / 256, 256, 0, stream>>>(obs, g, carma, theta, kappa, wsf, n);
        ekf_init_states<<<(C * 12 + 63) / 64, 64, 0, stream>>>(stA, C, w0, P0);
        // K = 4 sweeps: 3 state-only + 1 output-writing.
        ekf_sweep<false><<<C, 64, 0, stream>>>(wsf, out, n, L, stA, stB,
                                               w0, P0, b0, b1, a1, kappa, xi, rho);
        ekf_sweep<false><<<C, 64, 0, stream>>>(wsf, out, n, L, stB, stA,
                                               w0, P0, b0, b1, a1, kappa, xi, rho);
        ekf_sweep<false><<<C, 64, 0, stream>>>(wsf, out, n, L, stA, stB,
                                               w0, P0, b0, b1, a1, kappa, xi, rho);
        ekf_sweep<true ><<<C, 64, 0, stream>>>(wsf, out, n, L, stB, stA,
                                               w0, P0, b0, b1, a1, kappa, xi, rho);
    } else {
        ekf_seq_raw<<<1, 64, 0, stream>>>(obs, g, carma, out, n,
                                          w0, P0, b0, b1, a1, kappa, theta, xi, rho);
    }
}

// Round 3
// 1168.817 us; speedup vs baseline: 24.1387x; 2.5419x over previous
//
#include <hip/hip_runtime.h>
#include <math.h>

// EKF, T sequential steps. Round-3: fused single-kernel parareal.
// C=256 chunks (1/thread, 4 waves on 4 SIMDs of one CU), L=T/C=512,
// K=16 Jacobi sweeps with LDS boundary exchange. Per-step transcendentals
// (2 exp) replaced by multiplicatively-tracked e=exp(-w0), sg=exp(w0/2)
// with cubic Taylor updates (|dw0|<1e-2/step), re-seeded exactly each sweep.

#define DTV (1.0f/262.0f)
#define C_CHUNKS 256
#define K_SWEEPS 16

__device__ __forceinline__ float softplus_f(float x) {
    return fmaxf(x, 0.0f) + log1pf(__expf(-fabsf(x)));
}

struct EKFConsts { float kap, d2, d2sq, f1, f2, xi2DT, crossDT, cw; };
struct EKFState  { float w0, w1, w2, p00, p01, p02, p11, p12, p22; };

__device__ __forceinline__ void load_consts(EKFConsts& c,
    const float* pb0, const float* pb1, const float* pa1,
    const float* pkappa, const float* pxi, const float* prho)
{
    float b0 = pb0[0], b1 = pb1[0], a1 = pa1[0];
    c.kap = softplus_f(pkappa[0]);
    float xi_  = softplus_f(pxi[0]);
    float rho_ = tanhf(prho[0]);
    float xi2  = xi_ * xi_;
    c.d2      = 1.0f - a1 * DTV;
    c.d2sq    = c.d2 * c.d2;
    c.f1      = b0 * DTV;
    c.f2      = b1 * DTV;
    c.xi2DT   = xi2 * DTV;
    c.crossDT = xi_ * rho_ * DTV;
    c.cw      = 0.5f * xi2 - c.kap;
}

// Transcendental-free step: e = exp(-w0), sg = exp(w0/2) carried as state.
__device__ __forceinline__ float4 ekf_step2(EKFState& s, float& e, float& sg,
    const EKFConsts& c, float obs, float kterm, float c0dt, float c1dt)
{
    const float ETA = 1e-6f, ETA2 = 2e-6f;

    float term = kterm * fminf(e, 1.0f);   // e>=0 so only upper clip matters
    float d0 = 1.0f - term;
    float tc = term + c.cw;                // cw = xi2/2 - kap
    float s2 = sg * sg;                    // sigma^2 = exp(w0)
    float s2DT = s2 * DTV;

    float w0p = fmaf(tc, DTV, s.w0);
    float w1p = s.w1 + fmaf(s.w2, DTV, c0dt);
    float w2p = fmaf(c.d2, s.w2, c1dt);

    float pp00 = fmaf(d0 * d0, s.p00, c.xi2DT) + ETA2;
    float pp01 = d0 * fmaf(DTV, s.p02, s.p01);
    float pp02 = fmaf(d0 * c.d2, s.p02, sg * c.crossDT);
    float pp11 = fmaf(DTV * DTV, s.p22, fmaf(2.0f * DTV, s.p12, s.p11)) + ETA2;
    float pp12 = c.d2 * fmaf(DTV, s.p22, s.p12);
    float pp22 = fmaf(c.d2sq, s.p22, s2DT) + ETA2;

    float sig2p = fmaf(s2DT, tc, s2);      // exp(w0p) ~= s2*(1+tc*DT)
    float u0 = fmaf(c.f1, pp01, c.f2 * pp02);
    float u1 = fmaf(c.f1, pp11, c.f2 * pp12);
    float u2 = fmaf(c.f1, pp12, c.f2 * pp22);
    float Q  = fmaf(c.f1, u1, fmaf(c.f2, u2, fmaf(sig2p, DTV, ETA2)));
    float rQ = __builtin_amdgcn_rcpf(Q);

    float xp = fmaf(c.f1, w1p, c.f2 * w2p);
    float g  = (obs - xp) * rQ;            // innov/Q

    float w0n = fmaf(u0, g, w0p);
    s.w1 = fmaf(u1, g, w1p);
    s.w2 = fmaf(u2, g, w2p);

    float v0 = rQ * u0, v1 = rQ * u1, v2 = rQ * u2;
    s.p00 = fmaf(-v0, u0, pp00) + ETA;
    s.p01 = fmaf(-v0, u1, pp01);
    s.p02 = fmaf(-v0, u2, pp02);
    s.p11 = fmaf(-v1, u1, pp11) + ETA;
    s.p12 = fmaf(-v1, u2, pp12);
    s.p22 = fmaf(-v2, u2, pp22) + ETA;

    // w0 increment (exact expression, no cancellation): dlt = tc*DT + u0*g
    float dlt = fmaf(u0, g, tc * DTV);
    s.w0 = w0n;
    // e *= exp(-dlt), sg *= exp(dlt/2): cubic Taylor, |dlt| ~ 1e-3
    float em = fmaf(dlt, fmaf(dlt, fmaf(dlt, -(1.0f/6.0f), 0.5f), -1.0f), 1.0f);
    e *= em;
    float h = 0.5f * dlt;
    float sp = fmaf(h, fmaf(h, fmaf(h, (1.0f/6.0f), 0.5f), 1.0f), 1.0f);
    sg *= sp;

    return make_float4(xp, w0n, s.w1, s.w2);
}

// Exact step (full transcendentals) for the fallback path.
__device__ __forceinline__ float4 ekf_step(EKFState& s, const EKFConsts& c,
                                           float obs, float kterm, float c0dt, float c1dt)
{
    const float ETA = 1e-6f, ETA2 = 2e-6f;
    float e = fminf(__expf(-s.w0), 1.0f);
    float term = kterm * e;
    term = (term != term) ? 0.0f : term;
    float d0 = 1.0f - term;
    float sg = __expf(0.5f * s.w0);
    float s2 = sg * sg, s2DT = s2 * DTV;
    float tc = term + c.cw;
    float w0p = fmaf(tc, DTV, s.w0);
    float w1p = s.w1 + fmaf(s.w2, DTV, c0dt);
    float w2p = fmaf(c.d2, s.w2, c1dt);
    float pp00 = fmaf(d0 * d0, s.p00, c.xi2DT) + ETA2;
    float pp01 = d0 * fmaf(DTV, s.p02, s.p01);
    float pp02 = fmaf(d0 * c.d2, s.p02, sg * c.crossDT);
    float pp11 = fmaf(DTV * DTV, s.p22, fmaf(2.0f * DTV, s.p12, s.p11)) + ETA2;
    float pp12 = c.d2 * fmaf(DTV, s.p22, s.p12);
    float pp22 = fmaf(c.d2sq, s.p22, s2DT) + ETA2;
    float sig2p = fmaf(s2DT, tc, s2);
    float u0 = fmaf(c.f1, pp01, c.f2 * pp02);
    float u1 = fmaf(c.f1, pp11, c.f2 * pp12);
    float u2 = fmaf(c.f1, pp12, c.f2 * pp22);
    float Q  = fmaf(c.f1, u1, fmaf(c.f2, u2, fmaf(sig2p, DTV, ETA2)));
    float rQ = __builtin_amdgcn_rcpf(Q);
    float xp = fmaf(c.f1, w1p, c.f2 * w2p);
    float g  = (obs - xp) * rQ;
    s.w0 = fmaf(u0, g, w0p);
    s.w1 = fmaf(u1, g, w1p);
    s.w2 = fmaf(u2, g, w2p);
    float v0 = rQ * u0, v1 = rQ * u1, v2 = rQ * u2;
    s.p00 = fmaf(-v0, u0, pp00) + ETA;
    s.p01 = fmaf(-v0, u1, pp01);
    s.p02 = fmaf(-v0, u2, pp02);
    s.p11 = fmaf(-v1, u1, pp11) + ETA;
    s.p12 = fmaf(-v1, u2, pp12);
    s.p22 = fmaf(-v2, u2, pp22) + ETA;
    return make_float4(xp, s.w0, s.w1, s.w2);
}

// Parallel pre-pass: pack (obs, kap*softplus(theta+g), c0*DT, c1*DT).
__global__ void ekf_pack(const float* __restrict__ obs, const float* __restrict__ g,
                         const float2* __restrict__ carma,
                         const float* __restrict__ ptheta, const float* __restrict__ pkappa,
                         float4* __restrict__ ws, int n)
{
    int i = blockIdx.x * blockDim.x + threadIdx.x;
    if (i >= n) return;
    float kap = softplus_f(pkappa[0]);
    float kt  = kap * softplus_f(ptheta[0] + g[i]);
    float2 cv = carma[i];
    ws[i] = make_float4(obs[i], kt, cv.x * DTV, cv.y * DTV);
}

// Run one chunk of `len` steps starting at packed stream p; W: write outputs.
template<bool W>
__device__ __forceinline__ void run_chunk(EKFState& s, const EKFConsts& c,
    const float4* __restrict__ p, float4* __restrict__ o, int len)
{
    float e  = __expf(-s.w0);        // exact seed each sweep: kills poly drift
    float sg = __expf(0.5f * s.w0);
    constexpr int U = 8;
    float4 buf[U];
    int t = 0;
    if (len >= U) {
        #pragma unroll
        for (int j = 0; j < U; ++j) buf[j] = p[j];
        for (t = 0; t + U <= len; t += U) {
            float4 nbuf[U];
            int base = (t + 2 * U <= len) ? (t + U) : t;
            #pragma unroll
            for (int j = 0; j < U; ++j) nbuf[j] = p[base + j];
            #pragma unroll
            for (int j = 0; j < U; ++j) {
                float4 x = buf[j];
                float4 r = ekf_step2(s, e, sg, c, x.x, x.y, x.z, x.w);
                if (W) o[t + j] = r;
            }
            #pragma unroll
            for (int j = 0; j < U; ++j) buf[j] = nbuf[j];
        }
    }
    for (; t < len; ++t) {
        float4 x = p[t];
        float4 r = ekf_step2(s, e, sg, c, x.x, x.y, x.z, x.w);
        if (W) o[t] = r;
    }
}

// Fused parareal: 1 block, 256 threads = 256 chunks, K sweeps, LDS exchange.
__global__ void __launch_bounds__(256, 1) ekf_parareal(
    const float4* __restrict__ ws, float4* __restrict__ out, int n, int L,
    const float* __restrict__ w0in, const float* __restrict__ P0,
    const float* __restrict__ pb0, const float* __restrict__ pb1,
    const float* __restrict__ pa1, const float* __restrict__ pkappa,
    const float* __restrict__ pxi, const float* __restrict__ prho)
{
    __shared__ float st[C_CHUNKS][12];
    int tid = threadIdx.x;
    EKFConsts c; load_consts(c, pb0, pb1, pa1, pkappa, pxi, prho);

    EKFState ic;
    ic.w0 = w0in[0]; ic.w1 = w0in[1]; ic.w2 = w0in[2];
    ic.p00 = P0[0]; ic.p01 = P0[1]; ic.p02 = P0[2];
    ic.p11 = P0[4]; ic.p12 = P0[5]; ic.p22 = P0[8];

    int t0 = tid * L;
    int len = min(t0 + L, n) - t0;
    if (len < 0) len = 0;
    const float4* p = ws + t0;
    float4* o = out + t0;

    EKFState s = ic;   // initial guess for every chunk = IC (chunk 0: exact)

    for (int k = 0; k < K_SWEEPS; ++k) {
        EKFState r = s;
        if (k == K_SWEEPS - 1) {
            if (len > 0) run_chunk<true>(r, c, p, o, len);
            break;
        }
        if (len > 0) run_chunk<false>(r, c, p, len ? o : o, len);
        // boundary exchange: start(chunk, k+1) = end(chunk-1, k)
        float* sp = st[tid];
        sp[0] = r.w0; sp[1] = r.w1; sp[2] = r.w2;
        sp[3] = r.p00; sp[4] = r.p01; sp[5] = r.p02;
        sp[6] = r.p11; sp[7] = r.p12; sp[8] = r.p22;
        __syncthreads();
        if (tid > 0) {
            const float* q = st[tid - 1];
            s.w0 = q[0]; s.w1 = q[1]; s.w2 = q[2];
            s.p00 = q[3]; s.p01 = q[4]; s.p02 = q[5];
            s.p11 = q[6]; s.p12 = q[7]; s.p22 = q[8];
        } else {
            s = ic;
        }
        __syncthreads();
    }
}

// Fallback: exact single-lane sequential pass over raw inputs.
__global__ void __launch_bounds__(64, 1) ekf_seq_raw(
    const float* __restrict__ obs, const float* __restrict__ g,
    const float2* __restrict__ carma, float4* __restrict__ out, int n,
    const float* __restrict__ w0in, const float* __restrict__ P0,
    const float* __restrict__ pb0, const float* __restrict__ pb1,
    const float* __restrict__ pa1, const float* __restrict__ pkappa,
    const float* __restrict__ ptheta, const float* __restrict__ pxi,
    const float* __restrict__ prho)
{
    if (threadIdx.x != 0) return;
    EKFConsts c; load_consts(c, pb0, pb1, pa1, pkappa, pxi, prho);
    EKFState s;
    s.w0 = w0in[0]; s.w1 = w0in[1]; s.w2 = w0in[2];
    s.p00 = P0[0]; s.p01 = P0[1]; s.p02 = P0[2];
    s.p11 = P0[4]; s.p12 = P0[5]; s.p22 = P0[8];
    float theta = ptheta[0];
    for (int t = 0; t < n; ++t) {
        float kt = c.kap * softplus_f(theta + g[t]);
        float2 cv = carma[t];
        out[t] = ekf_step(s, c, obs[t], kt, cv.x * DTV, cv.y * DTV);
    }
}

extern "C" void kernel_launch(void* const* d_in, const int* in_sizes, int n_in,
                              void* d_out, int out_size, void* d_ws, size_t ws_size,
                              hipStream_t stream)
{
    const float*  obs   = (const float*)d_in[0];
    const float*  g     = (const float*)d_in[1];
    const float2* carma = (const float2*)d_in[2];
    const float*  w0    = (const float*)d_in[3];
    const float*  P0    = (const float*)d_in[4];
    const float*  b0    = (const float*)d_in[5];
    const float*  b1    = (const float*)d_in[6];
    const float*  a1    = (const float*)d_in[7];
    const float*  kappa = (const float*)d_in[8];
    const float*  theta = (const float*)d_in[9];
    const float*  xi    = (const float*)d_in[10];
    const float*  rho   = (const float*)d_in[11];
    int n = in_sizes[0];
    float4* out = (float4*)d_out;

    int L = (n + C_CHUNKS - 1) / C_CHUNKS;          // 512 for T=131072
    size_t need = (size_t)n * sizeof(float4);

    if (ws_size >= need && n >= C_CHUNKS) {
        float4* wsf = (float4*)d_ws;
        ekf_pack<<<(n + 255) / 256, 256, 0, stream>>>(obs, g, carma, theta, kappa, wsf, n);
        ekf_parareal<<<1, 256, 0, stream>>>(wsf, out, n, L,
                                            w0, P0, b0, b1, a1, kappa, xi, rho);
    } else {
        ekf_seq_raw<<<1, 64, 0, stream>>>(obs, g, carma, out, n,
                                          w0, P0, b0, b1, a1, kappa, theta, xi, rho);
    }
}